// Round 9
// baseline (325.520 us; speedup 1.0000x reference)
//
#include <hip/hip_runtime.h>
#include <math.h>

#define B_SZ  8192
#define KD    256
#define NCLS  32
#define NT    64                 // 128-row tiles per dim
#define NPAIRS 2080              // NT*(NT+1)/2 triangle tiles
#define SQRT_INVT 3.16227766016838f   // sqrt(10): fold 1/T into normalized rows
#define SCALE_E 1024.0f          // fixed-point scale for class sums
#define SCALE_P 524288.0f        // fixed-point scale for positive-sim sums

typedef __attribute__((ext_vector_type(8))) short short8;
typedef __attribute__((ext_vector_type(4))) float f32x4;

static __device__ __forceinline__ unsigned short f2bf(float f) {
    unsigned u = __float_as_uint(f);
    return (unsigned short)((u + 0x7FFF + ((u >> 16) & 1)) >> 16);   // RNE
}
static __device__ __forceinline__ float bf2f(unsigned short h) {
    return __uint_as_float((unsigned)h << 16);
}

// ---------------- kernel 1: normalize+scale rows, emit combined [hi(256)|lo(256)] bf16 ----------------
__global__ void prep_kernel(const float* __restrict__ feat, unsigned short* __restrict__ Fhl) {
    int row  = blockIdx.x * 4 + (threadIdx.x >> 6);
    int lane = threadIdx.x & 63;
    const float4 v = ((const float4*)(feat + (size_t)row * KD))[lane];
    float s = v.x * v.x + v.y * v.y + v.z * v.z + v.w * v.w;
    #pragma unroll
    for (int off = 1; off < 64; off <<= 1) s += __shfl_xor(s, off, 64);
    float rn = rsqrtf(s) * SQRT_INVT;
    float fn[4] = {v.x * rn, v.y * rn, v.z * rn, v.w * rn};
    ushort4 hi, lo;
    unsigned short* hp = (unsigned short*)&hi;
    unsigned short* lp = (unsigned short*)&lo;
    #pragma unroll
    for (int e = 0; e < 4; e++) {
        unsigned short h = f2bf(fn[e]);
        hp[e] = h;
        lp[e] = f2bf(fn[e] - bf2f(h));
    }
    ((ushort4*)(Fhl + (size_t)row * 512))[lane]       = hi;   // cols 0..255  = hi
    ((ushort4*)(Fhl + (size_t)row * 512 + 256))[lane] = lo;   // cols 256..511 = lo
}

// ---------------- kernel 2: global per-class counts ----------------
__global__ void count_kernel(const int* __restrict__ labels, int* __restrict__ counts) {
    __shared__ int sc[NCLS];
    int t = threadIdx.x;
    if (t < NCLS) sc[t] = 0;
    __syncthreads();
    for (int i = t; i < B_SZ; i += 256) atomicAdd(&sc[labels[i]], 1);
    __syncthreads();
    if (t < NCLS) counts[t] = sc[t];
}

// ---------------- kernel 3: triangle sim GEMM (it<=jt) + two-sided MFMA class reduce ----------------
// 2080 blocks (one 128x128 tile each, 2 resident/CU), 256 threads = 4 waves 2x2; wave owns 64x64.
// Off-diagonal tiles scatter BOTH i-side and j-side (via in-LDS E^T) class sums.
// All cross-block accumulation via int32 fixed-point atomics (deterministic).
__global__ __launch_bounds__(256, 2) void sim_kernel(
    const unsigned short* __restrict__ Fhl, const int* __restrict__ labels,
    int* __restrict__ pcls_int, int* __restrict__ spos_int)
{
    __shared__ __align__(16) unsigned short sbuf[2][2][128 * 64];  // 64KB: [buf][A/B]
    __shared__ int slab_j[128];
    __shared__ int slab_i[128];

    // bijective XCD swizzle (2080 % 8 == 0), then triangle decode
    const int bid = blockIdx.x;
    const int idx = (bid & 7) * (NPAIRS >> 3) + (bid >> 3);
    int it = (int)((129.0 - sqrt(129.0 * 129.0 - 8.0 * (double)idx)) * 0.5);
    it = it < 0 ? 0 : (it > 63 ? 63 : it);
    while (it > 0 && it * (129 - it) / 2 > idx) --it;
    while ((it + 1) * (128 - it) / 2 <= idx) ++it;
    const int jt = it + (idx - it * (129 - it) / 2);
    const bool diag = (it == jt);
    const int i0 = it * 128;
    const int j0 = jt * 128;

    const int t    = threadIdx.x;
    const int wave = t >> 6;
    const int lane = t & 63;
    const int wr   = wave >> 1;      // 0..1 -> 64-row (i) half
    const int wc   = wave & 1;       // 0..1 -> 64-col (j) half
    const int l15  = lane & 15;
    const int l4   = lane >> 4;

    const int rT = t >> 3;    // row-within-32 staged per quarter
    const int s8 = t & 7;     // physical 16B slot

    auto STAGE = [&](int buf, int kc) {
        #pragma unroll
        for (int a = 0; a < 4; ++a) {
            int r   = a * 32 + rT;
            int sl  = s8 ^ (r & 7);                         // logical slot (involution)
            int col = kc + (sl & 3) * 8 + ((sl & 4) << 6);  // slots 0-3 hi, 4-7 lo (+256)
            const unsigned short* gA = Fhl + (size_t)(i0 + r) * 512 + col;
            char* lA = (char*)&sbuf[buf][0][0] + a * 4096 + wave * 1024;
            __builtin_amdgcn_global_load_lds(
                (const __attribute__((address_space(1))) void*)gA,
                (__attribute__((address_space(3))) void*)lA, 16, 0, 0);
            const unsigned short* gB = Fhl + (size_t)(j0 + r) * 512 + col;
            char* lB = (char*)&sbuf[buf][1][0] + a * 4096 + wave * 1024;
            __builtin_amdgcn_global_load_lds(
                (const __attribute__((address_space(1))) void*)gB,
                (__attribute__((address_space(3))) void*)lB, 16, 0, 0);
        }
    };

    STAGE(0, 0);
    if (t < 128) slab_i[t] = labels[i0 + t];
    else if (t < 256) slab_j[t - 128] = labels[j0 + (t - 128)];

    int labi[4];
    #pragma unroll
    for (int m = 0; m < 4; m++) labi[m] = labels[i0 + wr * 64 + m * 16 + l15];

    f32x4 acc[4][4];
    #pragma unroll
    for (int m = 0; m < 4; m++)
        #pragma unroll
        for (int n = 0; n < 4; n++)
            acc[m][n] = (f32x4){0.f, 0.f, 0.f, 0.f};

    __syncthreads();                    // stage0 landed (vmcnt drained) + slabs visible

    // ---- 2-phase pipelined K-loop: 8 steps of BK=32, 3 products ----
    #pragma unroll 1
    for (int ks = 0; ks < 8; ++ks) {
        if (ks < 7) STAGE((ks + 1) & 1, (ks + 1) * 32);
        const unsigned short* pA = &sbuf[ks & 1][0][0];
        const unsigned short* pB = &sbuf[ks & 1][1][0];
        short8 bh[4], bl[4];
        #pragma unroll
        for (int n = 0; n < 4; ++n) {
            int r = wc * 64 + n * 16 + l15;
            bh[n] = *(const short8*)&pB[r * 64 + ((l4 ^ (r & 7)) * 8)];
            bl[n] = *(const short8*)&pB[r * 64 + (((4 + l4) ^ (r & 7)) * 8)];
        }
        __builtin_amdgcn_s_setprio(1);
        #pragma unroll
        for (int m = 0; m < 4; ++m) {
            int r = wr * 64 + m * 16 + l15;
            short8 ah = *(const short8*)&pA[r * 64 + ((l4 ^ (r & 7)) * 8)];
            short8 al = *(const short8*)&pA[r * 64 + (((4 + l4) ^ (r & 7)) * 8)];
            #pragma unroll
            for (int n = 0; n < 4; ++n) {
                // swapped operands: q indexes j. products: BhAh + BhAl + BlAh
                acc[m][n] = __builtin_amdgcn_mfma_f32_16x16x32_bf16(bh[n], ah, acc[m][n], 0, 0, 0);
                acc[m][n] = __builtin_amdgcn_mfma_f32_16x16x32_bf16(bh[n], al, acc[m][n], 0, 0, 0);
                acc[m][n] = __builtin_amdgcn_mfma_f32_16x16x32_bf16(bl[n], ah, acc[m][n], 0, 0, 0);
            }
        }
        __builtin_amdgcn_s_setprio(0);
        __syncthreads();   // drains next stage; swaps buffers
    }

    // ---- epilogue: sim -> spos atomics (both sides if off-diag) + E=exp ----
    #pragma unroll
    for (int m = 0; m < 4; m++) {
        const int il = wr * 64 + m * 16 + l15;
        #pragma unroll
        for (int n = 0; n < 4; n++) {
            const int jb = wc * 64 + n * 16 + l4 * 4;
            int4 lj = *(const int4*)&slab_j[jb];
            const int* ljp = (const int*)&lj;
            #pragma unroll
            for (int q = 0; q < 4; q++) {
                const int jl = jb + q;
                float sim = acc[m][n][q];            // already scaled by 1/T
                bool self = diag && (il == jl);
                if (!self && ljp[q] == labi[m]) {
                    int sq = __float2int_rn(sim * SCALE_P);
                    atomicAdd(&spos_int[i0 + il], sq);
                    if (!diag) atomicAdd(&spos_int[j0 + jl], sq);
                }
                acc[m][n][q] = self ? 0.0f : __expf(sim);
            }
        }
    }

    // one-hot fragments: hf_j over this wave's 64 j-cols, hf_i over its 64 i-rows
    short8 hf_j[2][2], hf_i[2][2];
    #pragma unroll
    for (int kk = 0; kk < 2; kk++) {
        const int jb = wc * 64 + kk * 32 + l4 * 8;
        const int ib = wr * 64 + kk * 32 + l4 * 8;
        int lvj[8], lvi[8];
        #pragma unroll
        for (int e = 0; e < 8; e++) { lvj[e] = slab_j[jb + e]; lvi[e] = slab_i[ib + e]; }
        #pragma unroll
        for (int cb = 0; cb < 2; cb++) {
            short8 hj, hi;
            #pragma unroll
            for (int e = 0; e < 8; e++) {
                hj[e] = (lvj[e] == cb * 16 + l15) ? (short)0x3F80 : (short)0;
                hi[e] = (lvi[e] == cb * 16 + l15) ? (short)0x3F80 : (short)0;
            }
            hf_j[kk][cb] = hj;
            hf_i[kk][cb] = hi;
        }
    }

    char* sE = (char*)&sbuf[1][0][0];   // 32KB: [128][256B] bf16, XOR-swizzled rows

    // ---- i-side: E rows=i (wave-private region: rows in wr-half) ----
    f32x4 cs_i[4][2];
    #pragma unroll
    for (int m = 0; m < 4; m++)
        #pragma unroll
        for (int cb = 0; cb < 2; cb++)
            cs_i[m][cb] = (f32x4){0.f, 0.f, 0.f, 0.f};

    #pragma unroll
    for (int copy = 0; copy < 2; copy++) {
        #pragma unroll
        for (int m = 0; m < 4; m++) {
            const int row = wr * 64 + m * 16 + l15;
            #pragma unroll
            for (int n = 0; n < 4; n++) {
                const int bc = (wc * 128 + n * 32 + l4 * 8) ^ ((row & 7) << 4);
                unsigned short b[4];
                #pragma unroll
                for (int q = 0; q < 4; q++) {
                    float e = acc[m][n][q];
                    unsigned short h = f2bf(e);
                    b[q] = copy == 0 ? h : f2bf(e - bf2f(h));
                }
                uint2 w;
                w.x = (unsigned)b[0] | ((unsigned)b[1] << 16);
                w.y = (unsigned)b[2] | ((unsigned)b[3] << 16);
                *(uint2*)(sE + (size_t)row * 256 + bc) = w;
            }
        }
        #pragma unroll
        for (int m = 0; m < 4; m++) {
            const int row = wr * 64 + m * 16 + l15;
            #pragma unroll
            for (int kk = 0; kk < 2; kk++) {
                const int bc = (wc * 128 + kk * 64 + l4 * 16) ^ ((row & 7) << 4);
                short8 ef = *(const short8*)(sE + (size_t)row * 256 + bc);
                #pragma unroll
                for (int cb = 0; cb < 2; cb++)
                    cs_i[m][cb] = __builtin_amdgcn_mfma_f32_16x16x32_bf16(
                        ef, hf_j[kk][cb], cs_i[m][cb], 0, 0, 0);
            }
        }
    }
    // dump i-side (int atomics; global latency hides under E^T phase)
    #pragma unroll
    for (int m = 0; m < 4; m++)
        #pragma unroll
        for (int cb = 0; cb < 2; cb++)
            #pragma unroll
            for (int q = 0; q < 4; q++) {
                const int ig = i0 + wr * 64 + m * 16 + l4 * 4 + q;
                atomicAdd(&pcls_int[ig * NCLS + cb * 16 + l15],
                          __float2int_rn(cs_i[m][cb][q] * SCALE_E));
            }

    // ---- j-side (off-diagonal only): E^T rows=j (wave-private: rows wc-half, cols wr-half) ----
    if (!diag) {
        __syncthreads();   // all waves done reading E before E^T overwrites

        f32x4 cs_j[4][2];
        #pragma unroll
        for (int m = 0; m < 4; m++)
            #pragma unroll
            for (int cb = 0; cb < 2; cb++)
                cs_j[m][cb] = (f32x4){0.f, 0.f, 0.f, 0.f};

        #pragma unroll
        for (int copy = 0; copy < 2; copy++) {
            #pragma unroll
            for (int m = 0; m < 4; m++) {
                const int colb = (wr * 64 + m * 16 + l15) * 2;   // i as byte col
                #pragma unroll
                for (int n = 0; n < 4; n++) {
                    unsigned short b[4];
                    #pragma unroll
                    for (int q = 0; q < 4; q++) {
                        float e = acc[m][n][q];
                        unsigned short h = f2bf(e);
                        b[q] = copy == 0 ? h : f2bf(e - bf2f(h));
                    }
                    #pragma unroll
                    for (int q = 0; q < 4; q++) {
                        const int row = wc * 64 + n * 16 + l4 * 4 + q;   // j as row
                        *(unsigned short*)(sE + (size_t)row * 256 + (colb ^ ((row & 7) << 4))) = b[q];
                    }
                }
            }
            #pragma unroll
            for (int m2 = 0; m2 < 4; m2++) {
                const int row = wc * 64 + m2 * 16 + l15;
                #pragma unroll
                for (int kk = 0; kk < 2; kk++) {
                    const int bc = (wr * 128 + kk * 64 + l4 * 16) ^ ((row & 7) << 4);
                    short8 ef = *(const short8*)(sE + (size_t)row * 256 + bc);
                    #pragma unroll
                    for (int cb = 0; cb < 2; cb++)
                        cs_j[m2][cb] = __builtin_amdgcn_mfma_f32_16x16x32_bf16(
                            ef, hf_i[kk][cb], cs_j[m2][cb], 0, 0, 0);
                }
            }
        }
        #pragma unroll
        for (int m2 = 0; m2 < 4; m2++)
            #pragma unroll
            for (int cb = 0; cb < 2; cb++)
                #pragma unroll
                for (int q = 0; q < 4; q++) {
                    const int jg = j0 + wc * 64 + m2 * 16 + l4 * 4 + q;
                    atomicAdd(&pcls_int[jg * NCLS + cb * 16 + l15],
                              __float2int_rn(cs_j[m2][cb][q] * SCALE_E));
                }
    }
}

// ---------------- kernel 4: per-anchor loss from int fixed-point sums ----------------
__global__ void loss_kernel(const int* __restrict__ pcls_int, const int* __restrict__ spos_int,
                            const int* __restrict__ counts, const int* __restrict__ labels,
                            float* __restrict__ loss_i, float* __restrict__ validf) {
    int i = blockIdx.x * blockDim.x + threadIdx.x;
    if (i >= B_SZ) return;
    int labi = labels[i];
    const int4* row = (const int4*)(pcls_int + (size_t)i * NCLS);
    float denom = 0.0f;
    #pragma unroll
    for (int w = 0; w < 8; w++) {
        int4 v = row[w];
        const int* vp = (const int*)&v;
        #pragma unroll
        for (int e = 0; e < 4; e++) {
            int c = w * 4 + e;
            int cnt = counts[c] - (c == labi ? 1 : 0);
            if (cnt > 0) denom += ((float)vp[e] * (1.0f / SCALE_E)) / (float)cnt;
        }
    }
    float psum = (float)spos_int[i] * (1.0f / SCALE_P);
    int P = counts[labi] - 1;
    bool valid = P > 0;
    float li = 0.0f;
    if (valid) li = logf(fmaxf(denom, 1e-30f)) - psum / (float)max(P, 1);
    loss_i[i] = li;
    validf[i] = valid ? 1.0f : 0.0f;
}

// ---------------- kernel 5: deterministic final reduction ----------------
__global__ void final_kernel(const float* __restrict__ loss_i, const float* __restrict__ validf,
                             float* __restrict__ out) {
    __shared__ float ssum[256];
    __shared__ float scnt[256];
    int t = threadIdx.x;
    float s = 0.0f, c = 0.0f;
    for (int i = t; i < B_SZ; i += 256) { s += loss_i[i]; c += validf[i]; }
    ssum[t] = s; scnt[t] = c;
    __syncthreads();
    #pragma unroll
    for (int off = 128; off > 0; off >>= 1) {
        if (t < off) { ssum[t] += ssum[t + off]; scnt[t] += scnt[t + off]; }
        __syncthreads();
    }
    if (t == 0) out[0] = (scnt[0] > 0.0f) ? ssum[0] / scnt[0] : 0.0f;
}

// ---------------- launch ----------------
extern "C" void kernel_launch(void* const* d_in, const int* in_sizes, int n_in,
                              void* d_out, int out_size, void* d_ws, size_t ws_size,
                              hipStream_t stream) {
    const float* feat   = (const float*)d_in[0];
    const int*   labels = (const int*)d_in[1];
    float*       out    = (float*)d_out;

    char* ws = (char*)d_ws;
    size_t off = 0;
    auto alloc = [&](size_t bytes) -> void* {
        void* p = ws + off;
        off = (off + bytes + 255) & ~(size_t)255;
        return p;
    };

    unsigned short* Fhl = (unsigned short*)alloc((size_t)B_SZ * 512 * 2);   // 8.4MB
    int*   counts   = (int*)alloc((size_t)NCLS * 4);
    int*   pcls_int = (int*)alloc((size_t)B_SZ * NCLS * 4);                 // 1MB
    int*   spos_int = (int*)alloc((size_t)B_SZ * 4);                        // 32KB
    float* loss_i   = (float*)alloc((size_t)B_SZ * 4);
    float* validf   = (float*)alloc((size_t)B_SZ * 4);

    hipMemsetAsync(pcls_int, 0, (size_t)B_SZ * NCLS * 4, stream);
    hipMemsetAsync(spos_int, 0, (size_t)B_SZ * 4, stream);
    prep_kernel<<<B_SZ / 4, 256, 0, stream>>>(feat, Fhl);
    count_kernel<<<1, 256, 0, stream>>>(labels, counts);
    sim_kernel<<<NPAIRS, 256, 0, stream>>>(Fhl, labels, pcls_int, spos_int);
    loss_kernel<<<B_SZ / 256, 256, 0, stream>>>(pcls_int, spos_int, counts, labels, loss_i, validf);
    final_kernel<<<1, 256, 0, stream>>>(loss_i, validf, out);
}